// Round 11
// baseline (5274.900 us; speedup 1.0000x reference)
//
#include <hip/hip_runtime.h>

// ---------------------------------------------------------------------------
// Bidirectional GRU (B=128, T=512, E=H=256) + linear head.
// Phase 1 (R9): LDS-shared wide-N gate table (2 dirs x 128 WGs).
// Phase 2 (R11): hidden-split recurrence across 32 WGs (dir x batch-group x
//   half). Wave owns 16 dims -> 4 GRU elems/lane (VALU halved), 24 MFMA/wave
//   (MFMA/SIMD halved). Partner WGs exchange h-halves per step through L3:
//   agent-scope 8B atomic stores/loads (bypass non-coherent per-XCD L2) +
//   per-WG step flag (release after barrier vmcnt drain / acquire spin).
//   Partner fragments feed MFMA directly from registers.
// ---------------------------------------------------------------------------

typedef float f32x4 __attribute__((ext_vector_type(4)));
typedef short s16x8 __attribute__((ext_vector_type(8)));

#define VOCAB   30000
#define GCOLS   1536
#define HB_STR  280     // bf16 elems per emb row in table kernel (560 B)
#define GP_STR  1032    // bf16 elems per xgS row (2064 B)
#define SRF     (-1.4426950408889634f)   // -log2(e), sigmoid gates
#define SNF     (2.8853900817779268f)    // 2*log2(e), tanh gate
#define G_BYTES (92160000ull)            // 30000*1536*2
#define XSLOT_U64 512                    // 4 KB per h-half slot, in ulongs

#if defined(__has_builtin)
#if __has_builtin(__builtin_amdgcn_cvt_pk_bf16_f32)
#define HAVE_PK 1
#endif
#endif

static __device__ __forceinline__ unsigned short f2bf(float f) {
    unsigned u = __builtin_bit_cast(unsigned, f);
    u += 0x7fffu + ((u >> 16) & 1u);            // RNE
    return (unsigned short)(u >> 16);
}
#ifdef HAVE_PK
typedef __bf16 bf16x2_t __attribute__((ext_vector_type(2)));
static __device__ __forceinline__ unsigned pk2(float a, float b) {
    bf16x2_t v = __builtin_amdgcn_cvt_pk_bf16_f32(a, b);
    return __builtin_bit_cast(unsigned, v);
}
#else
static __device__ __forceinline__ unsigned pk2(float a, float b) {
    return (unsigned)f2bf(a) | ((unsigned)f2bf(b) << 16);
}
#endif
static __device__ __forceinline__ float bf_lo(unsigned v) {
    return __builtin_bit_cast(float, v << 16);
}
static __device__ __forceinline__ float bf_hi(unsigned v) {
    return __builtin_bit_cast(float, v & 0xffff0000u);
}
static __device__ __forceinline__ s16x8 pack_bf8(float4 a, float4 b, float s) {
    union { s16x8 v; unsigned u[4]; } r;
    r.u[0] = pk2(a.x * s, a.y * s); r.u[1] = pk2(a.z * s, a.w * s);
    r.u[2] = pk2(b.x * s, b.y * s); r.u[3] = pk2(b.z * s, b.w * s);
    return r.v;
}
static __device__ __forceinline__ f32x4 mfma16(s16x8 a, s16x8 b, f32x4 c) {
    return __builtin_amdgcn_mfma_f32_16x16x32_bf16(a, b, c, 0, 0, 0);
}
static __device__ __forceinline__ float sig2(float x) {      // 1/(1+2^x)
    return __builtin_amdgcn_rcpf(1.0f + __builtin_amdgcn_exp2f(x));
}
static __device__ __forceinline__ void gload_lds16(const unsigned short* g, unsigned short* l) {
    __builtin_amdgcn_global_load_lds(
        (const __attribute__((address_space(1))) unsigned*)g,
        (__attribute__((address_space(3))) unsigned*)l, 16, 0, 0);
}
static __device__ __forceinline__ void xstore8(unsigned long long* p, unsigned long long v) {
    __hip_atomic_store(p, v, __ATOMIC_RELAXED, __HIP_MEMORY_SCOPE_AGENT);
}
static __device__ __forceinline__ unsigned long long xload8(const unsigned long long* p) {
    return __hip_atomic_load(p, __ATOMIC_RELAXED, __HIP_MEMORY_SCOPE_AGENT);
}

// permuted col c = d*768 + (6*w8 + 2*gate + half)*16 + (dim&15);
// orig gate row = gate*256 + 32*w8 + half*16 + (dim&15).

// ---------------------------------------------------------------------------
// Phase 1: gate table (R9).  grid (2 dirs, 128 M-slices), 512 threads.
// ---------------------------------------------------------------------------
__global__ __launch_bounds__(512, 2)
void gru_table_kernel(const float* __restrict__ emb,
                      const float* __restrict__ Wih_f, const float* __restrict__ bih_f,
                      const float* __restrict__ bhh_f,
                      const float* __restrict__ Wih_b, const float* __restrict__ bih_b,
                      const float* __restrict__ bhh_b,
                      unsigned short* __restrict__ G) {
    __shared__ unsigned short aS[2][16 * HB_STR];    // dbuf emb tile (bf16)

    const int tid  = threadIdx.x;
    const int lane = tid & 63;
    const int w    = tid >> 6;       // wave 0..7 -> N-tiles 6w..6w+5
    const int u    = lane & 15;
    const int q    = lane >> 4;
    const int d    = blockIdx.x;     // 0 fwd, 1 bwd
    const int by   = blockIdx.y;     // 0..127

    const float* Wih = d ? Wih_b : Wih_f;
    const float* bih = d ? bih_b : bih_f;
    const float* bhh = d ? bhh_b : bhh_f;

    s16x8 breg[48];
    float beta[6];
#pragma unroll
    for (int t = 0; t < 6; ++t) {
        const int orig = (t >> 1) * 256 + 32 * w + ((t & 1) << 4) + u;
        const float scl = (t < 4) ? SRF : SNF;
        beta[t] = (bih[orig] + ((t < 4) ? bhh[orig] : 0.0f)) * scl;
#pragma unroll
        for (int kt = 0; kt < 8; ++kt) {
            const float* p = Wih + orig * 256 + kt * 32 + q * 8;
            breg[t * 8 + kt] =
                pack_bf8(*(const float4*)p, *(const float4*)(p + 4), scl);
        }
    }

    const int srow = tid >> 5;
    const int sc8  = (tid & 31) * 8;

    {
        const float* p = emb + (size_t)(by * 16 + srow) * 256 + sc8;
        float4 e0 = *(const float4*)p, e1 = *(const float4*)(p + 4);
        unsigned* dp = (unsigned*)&aS[0][srow * HB_STR + sc8];
        dp[0] = pk2(e0.x, e0.y); dp[1] = pk2(e0.z, e0.w);
        dp[2] = pk2(e1.x, e1.y); dp[3] = pk2(e1.z, e1.w);
    }
    __syncthreads();

    const size_t colbase = (size_t)(d * 48 + 6 * w) * 16 + u;

    for (int i = 0;; ++i) {
        const int mt = by + i * 128;
        if (mt >= 1875) break;
        const int mtn = mt + 128;
        const bool has_next = (mtn < 1875);
        const int buf = i & 1;

        float4 e0, e1;
        if (has_next) {
            const float* p = emb + (size_t)(mtn * 16 + srow) * 256 + sc8;
            e0 = *(const float4*)p;
            e1 = *(const float4*)(p + 4);
        }

        const int v0 = mt * 16;
#pragma unroll
        for (int l = 0; l < 2; ++l) {
            f32x4 a0 = {0.f, 0.f, 0.f, 0.f}, a1 = a0, a2 = a0;
#pragma unroll
            for (int kt = 0; kt < 8; ++kt) {
                s16x8 af = *(const s16x8*)&aS[buf][u * HB_STR + kt * 32 + q * 8];
                a0 = mfma16(af, breg[(0 + l) * 8 + kt], a0);
                a1 = mfma16(af, breg[(2 + l) * 8 + kt], a1);
                a2 = mfma16(af, breg[(4 + l) * 8 + kt], a2);
            }
#pragma unroll
            for (int g = 0; g < 3; ++g) {
                const f32x4 a = (g == 0) ? a0 : (g == 1) ? a1 : a2;
                const int t = 2 * g + l;
                unsigned short* gp = G + (size_t)(v0 + q * 4) * GCOLS + colbase + t * 16;
#pragma unroll
                for (int r = 0; r < 4; ++r)
                    gp[(size_t)r * GCOLS] = f2bf(a[r] + beta[t]);
            }
        }
        if (has_next) {
            unsigned* dp = (unsigned*)&aS[buf ^ 1][srow * HB_STR + sc8];
            dp[0] = pk2(e0.x, e0.y); dp[1] = pk2(e0.z, e0.w);
            dp[2] = pk2(e1.x, e1.y); dp[3] = pk2(e1.z, e1.w);
        }
        __syncthreads();
    }
}

// ---------------------------------------------------------------------------
// Phase 2: hidden-split recurrence. grid = 32: bx = d*16 + g*2 + e.
// WG owns dims [e*128, e*128+128); wave w owns 16 dims. 512 threads.
// ---------------------------------------------------------------------------
__global__ __launch_bounds__(512, 2)
void gru_rnn_kernel(const int* __restrict__ inp,
                    const float* __restrict__ Whh_f, const float* __restrict__ bhh_f,
                    const float* __restrict__ Whh_b, const float* __restrict__ bhh_b,
                    const float* __restrict__ W_lin, const float* __restrict__ b_lin,
                    const unsigned short* __restrict__ G,
                    unsigned long long* __restrict__ X,
                    unsigned int* __restrict__ flags,
                    float* __restrict__ out) {
    __shared__ int            toks[16][513];          // 32.8 KB
    __shared__ unsigned short hBo[2][16][136];        // 8.7 KB own-half h
    __shared__ unsigned short xgS[2][16][GP_STR];     // 66.0 KB dbuf xg
    __shared__ float          bhnS[128];
    __shared__ float          hs[16][132];            // 8.4 KB epilogue

    const int tid  = threadIdx.x;
    const int lane = tid & 63;
    const int w    = tid >> 6;          // wave 0..7: local dims [16w,16w+16)
    const int b    = lane & 15;         // batch (B n-col / C col)
    const int u    = lane & 15;         // A-row m within 16-dim tile
    const int q    = lane >> 4;
    const int bx   = blockIdx.x;
    const int d    = bx >> 4;           // direction
    const int gp_  = (bx >> 1) & 7;     // batch group
    const int e    = bx & 1;            // hidden half
    const int b0   = gp_ * 16;
    const int D0   = e * 128 + 16 * w;  // wave's global dim base
    const int w8   = D0 >> 5;
    const int hf8  = w & 1;             // 16-block within 32-block

    const float* Whh = d ? Whh_b : Whh_f;
    const float* bhh = d ? bhh_b : bhh_f;

    // W_hh A-frags: 3 gates x 8 global k-chunks = 24 frags (96 VGPRs)
    s16x8 wreg[24];
#pragma unroll
    for (int gg = 0; gg < 3; ++gg) {
        const int orig = gg * 256 + D0 + u;
        const float scl = (gg < 2) ? SRF : SNF;
#pragma unroll
        for (int ktg = 0; ktg < 8; ++ktg) {
            const float* p = Whh + orig * 256 + ktg * 32 + q * 8;
            wreg[gg * 8 + ktg] =
                pack_bf8(*(const float4*)p, *(const float4*)(p + 4), scl);
        }
    }

    for (int i = tid; i < 16 * 512; i += 512) {
        int bb = i >> 9, t = i & 511;
        toks[bb][t] = inp[(b0 + bb) * 512 + t];
    }
    for (int i = tid; i < 2 * 16 * 136; i += 512) ((unsigned short*)hBo)[i] = 0;
    if (tid < 128) bhnS[tid] = SNF * bhh[512 + e * 128 + tid];
    __syncthreads();

    // prologue: stage step-0 xg (wave w stages batches 2w, 2w+1; full window)
    {
        int t0 = d ? 511 : 0;
#pragma unroll
        for (int j = 0; j < 2; ++j) {
            int bb = 2 * w + j;
            int tok = toks[bb][t0];
            const unsigned short* gb = G + (size_t)tok * GCOLS + (d ? 512 : 0) + lane * 8;
            gload_lds16(gb,       &xgS[0][bb][0]);
            gload_lds16(gb + 512, &xgS[0][bb][512]);
        }
    }
    __syncthreads();   // xgS[0] valid

    unsigned long long*       Xs = X + (size_t)bx * 2 * XSLOT_U64;
    const unsigned long long* Xp = X + (size_t)(bx ^ 1) * 2 * XSLOT_U64;
    volatile unsigned int* pflag = &flags[bx ^ 1];

    const int xbase = d * 256 + (6 * w8 + hf8) * 16 + 4 * q;  // +32 per gate
    float hreg[4] = {0.f, 0.f, 0.f, 0.f};

#pragma unroll 2
    for (int ts = 0; ts < 512; ++ts) {
        const int par = ts & 1, npar = par ^ 1;
        // 1) stage next step's xg (async, zero VGPR)
        {
            int s1 = (ts < 511) ? ts + 1 : 511;
            int t1 = d ? 511 - s1 : s1;
#pragma unroll
            for (int j = 0; j < 2; ++j) {
                int bb = 2 * w + j;
                int tok = toks[bb][t1];
                const unsigned short* gb = G + (size_t)tok * GCOLS + (d ? 512 : 0) + lane * 8;
                gload_lds16(gb,       &xgS[npar][bb][0]);
                gload_lds16(gb + 512, &xgS[npar][bb][512]);
            }
        }
        // 2) wait for partner's h_ts (flag >= ts; slot0 pre-zeroed => h_0 free)
        while (__hip_atomic_load(&flags[bx ^ 1], __ATOMIC_ACQUIRE,
                                 __HIP_MEMORY_SCOPE_AGENT) < (unsigned)ts)
            __builtin_amdgcn_s_sleep(2);
        // 3) issue partner-half loads (8 x 8B agent-scope, L2-bypass)
        unsigned long long pu[4][2];
        {
            const unsigned long long* xp = Xp + par * XSLOT_U64 + b * 32 + q * 2;
#pragma unroll
            for (int c = 0; c < 4; ++c) {
                pu[c][0] = xload8(xp + c * 8);
                pu[c][1] = xload8(xp + c * 8 + 1);
            }
        }
        // 4) own-half MFMAs (LDS) — overlap partner-load latency
        f32x4 ar = {0.f, 0.f, 0.f, 0.f};
        f32x4 az = {0.f, 0.f, 0.f, 0.f};
        f32x4 an = *(const f32x4*)&bhnS[16 * w + 4 * q];
#pragma unroll
        for (int c = 0; c < 4; ++c) {
            s16x8 hf = *(const s16x8*)&hBo[par][b][c * 32 + q * 8];
            const int ktg = e * 4 + c;
            ar = mfma16(wreg[0 * 8 + ktg], hf, ar);
            az = mfma16(wreg[1 * 8 + ktg], hf, az);
            an = mfma16(wreg[2 * 8 + ktg], hf, an);
        }
        // 5) partner-half MFMAs (register frags)
#pragma unroll
        for (int c = 0; c < 4; ++c) {
            union { unsigned long long u[2]; s16x8 v; } pfr;
            pfr.u[0] = pu[c][0]; pfr.u[1] = pu[c][1];
            const int ktg = (e ^ 1) * 4 + c;
            ar = mfma16(wreg[0 * 8 + ktg], pfr.v, ar);
            az = mfma16(wreg[1 * 8 + ktg], pfr.v, az);
            an = mfma16(wreg[2 * 8 + ktg], pfr.v, an);
        }
        // 6) pointwise GRU (4 elems/lane)
        {
            const unsigned short* xrow = &xgS[par][b][xbase];
            uint2 uxr = *(const uint2*)&xrow[0];
            uint2 uxz = *(const uint2*)&xrow[32];
            uint2 uxn = *(const uint2*)&xrow[64];
            float xr[4] = {bf_lo(uxr.x), bf_hi(uxr.x), bf_lo(uxr.y), bf_hi(uxr.y)};
            float xz[4] = {bf_lo(uxz.x), bf_hi(uxz.x), bf_lo(uxz.y), bf_hi(uxz.y)};
            float xn[4] = {bf_lo(uxn.x), bf_hi(uxn.x), bf_lo(uxn.y), bf_hi(uxn.y)};
#pragma unroll
            for (int r = 0; r < 4; ++r) {
                float rg = sig2(xr[r] + ar[r]);
                float zg = sig2(xz[r] + az[r]);
                float tg = sig2(fmaf(rg, an[r], xn[r]));
                float ng = fmaf(-2.0f, tg, 1.0f);
                hreg[r] = fmaf(zg, hreg[r] - ng, ng);
            }
        }
        // 7) publish h_new: local LDS (own kt source) + global X (partner)
        {
            unsigned p0 = pk2(hreg[0], hreg[1]);
            unsigned p1 = pk2(hreg[2], hreg[3]);
            *(uint2*)&hBo[npar][b][16 * w + 4 * q] = make_uint2(p0, p1);
            xstore8(Xs + npar * XSLOT_U64 + b * 32 + 4 * w + q,
                    (unsigned long long)p0 | ((unsigned long long)p1 << 32));
        }
        // 8) barrier drains vmcnt (X stores complete) + lgkm; then release flag
        __syncthreads();
        if (tid == 0)
            __hip_atomic_store(&flags[bx], (unsigned)(ts + 1), __ATOMIC_RELEASE,
                               __HIP_MEMORY_SCOPE_AGENT);
    }
    (void)pflag;

    // epilogue: partial dot over own 128 dims; atomicAdd across 4 WGs/(g)
    *(f32x4*)&hs[b][16 * w + 4 * q] =
        f32x4{hreg[0], hreg[1], hreg[2], hreg[3]};
    __syncthreads();
    if (tid < 160) {
        int bb = tid / 10;
        int c  = tid - bb * 10;
        float acc = (d == 0 && e == 0) ? b_lin[c] : 0.0f;
        const float* wl = W_lin + c * 512 + d * 256 + e * 128;
        const float* hp = &hs[bb][0];
        for (int i = 0; i < 128; ++i) acc += hp[i] * wl[i];
        atomicAdd(&out[(b0 + bb) * 10 + c], acc);
    }
}

// ---------------------------------------------------------------------------
extern "C" void kernel_launch(void* const* d_in, const int* in_sizes, int n_in,
                              void* d_out, int out_size, void* d_ws, size_t ws_size,
                              hipStream_t stream) {
    const int*   inp   = (const int*)d_in[0];
    const float* emb   = (const float*)d_in[1];
    const float* Wih_f = (const float*)d_in[2];
    const float* Whh_f = (const float*)d_in[3];
    const float* bih_f = (const float*)d_in[4];
    const float* bhh_f = (const float*)d_in[5];
    const float* Wih_b = (const float*)d_in[6];
    const float* Whh_b = (const float*)d_in[7];
    const float* bih_b = (const float*)d_in[8];
    const float* bhh_b = (const float*)d_in[9];
    const float* W_lin = (const float*)d_in[10];
    const float* b_lin = (const float*)d_in[11];
    float* out = (float*)d_out;

    unsigned short*     G     = (unsigned short*)d_ws;              // 92.16 MB
    unsigned long long* X     = (unsigned long long*)((char*)d_ws + G_BYTES);
    unsigned int*       flags = (unsigned int*)((char*)d_ws + G_BYTES + 32ull * 2 * XSLOT_U64 * 8);

    hipMemsetAsync(d_out, 0, (size_t)out_size * sizeof(float), stream);
    // zero exchange slots (h_0 = 0) + flags (step counters)
    hipMemsetAsync((char*)d_ws + G_BYTES, 0, 32ull * 2 * XSLOT_U64 * 8 + 32 * sizeof(unsigned), stream);
    hipLaunchKernelGGL(gru_table_kernel, dim3(2, 128), dim3(512), 0, stream,
                       emb, Wih_f, bih_f, bhh_f, Wih_b, bih_b, bhh_b, G);
    hipLaunchKernelGGL(gru_rnn_kernel, dim3(32), dim3(512), 0, stream,
                       inp, Whh_f, bhh_f, Whh_b, bhh_b, W_lin, b_lin, G, X, flags, out);
}

// Round 12
// 1061.866 us; speedup vs baseline: 4.9676x; 4.9676x over previous
//
#include <hip/hip_runtime.h>

// ---------------------------------------------------------------------------
// Bidirectional GRU (B=128, T=512, E=H=256) + linear head.
// Phase 1 (R9): LDS-shared wide-N gate table (2 dirs x 128 WGs).
// Phase 2 (R12): R9/R6 core with GATE-MAJOR MFMA ordering per l-half:
//   pass A = r+z chains (16 MFMA) -> rg/zg sig2s overlap pass B = n chain
//   (8 MFMA). xg read from LDS at step TOP (staged previous step, so no
//   latency on critical path). Same arithmetic, same sync; schedule only.
// ---------------------------------------------------------------------------

typedef float f32x4 __attribute__((ext_vector_type(4)));
typedef short s16x8 __attribute__((ext_vector_type(8)));

#define VOCAB   30000
#define GCOLS   1536
#define HB_STR  280     // bf16 elems per h/emb row (560 B)
#define HBUF    (16 * HB_STR)
#define GP_STR  1032    // bf16 elems per xgS row (2064 B)
#define HS_STR  260     // f32 elems per h row for epilogue
#define SRF     (-1.4426950408889634f)   // -log2(e), sigmoid gates
#define SNF     (2.8853900817779268f)    // 2*log2(e), tanh gate

#if defined(__has_builtin)
#if __has_builtin(__builtin_amdgcn_cvt_pk_bf16_f32)
#define HAVE_PK 1
#endif
#endif

static __device__ __forceinline__ unsigned short f2bf(float f) {
    unsigned u = __builtin_bit_cast(unsigned, f);
    u += 0x7fffu + ((u >> 16) & 1u);            // RNE
    return (unsigned short)(u >> 16);
}
#ifdef HAVE_PK
typedef __bf16 bf16x2_t __attribute__((ext_vector_type(2)));
static __device__ __forceinline__ unsigned pk2(float a, float b) {
    bf16x2_t v = __builtin_amdgcn_cvt_pk_bf16_f32(a, b);
    return __builtin_bit_cast(unsigned, v);
}
#else
static __device__ __forceinline__ unsigned pk2(float a, float b) {
    return (unsigned)f2bf(a) | ((unsigned)f2bf(b) << 16);
}
#endif
static __device__ __forceinline__ float bf_lo(unsigned v) {
    return __builtin_bit_cast(float, v << 16);
}
static __device__ __forceinline__ float bf_hi(unsigned v) {
    return __builtin_bit_cast(float, v & 0xffff0000u);
}
static __device__ __forceinline__ s16x8 pack_bf8(float4 a, float4 b, float s) {
    union { s16x8 v; unsigned u[4]; } r;
    r.u[0] = pk2(a.x * s, a.y * s); r.u[1] = pk2(a.z * s, a.w * s);
    r.u[2] = pk2(b.x * s, b.y * s); r.u[3] = pk2(b.z * s, b.w * s);
    return r.v;
}
static __device__ __forceinline__ f32x4 mfma16(s16x8 a, s16x8 b, f32x4 c) {
    return __builtin_amdgcn_mfma_f32_16x16x32_bf16(a, b, c, 0, 0, 0);
}
static __device__ __forceinline__ float sig2(float x) {      // 1/(1+2^x)
    return __builtin_amdgcn_rcpf(1.0f + __builtin_amdgcn_exp2f(x));
}
static __device__ __forceinline__ void gload_lds16(const unsigned short* g, unsigned short* l) {
    __builtin_amdgcn_global_load_lds(
        (const __attribute__((address_space(1))) unsigned*)g,
        (__attribute__((address_space(3))) unsigned*)l, 16, 0, 0);
}

// permuted col c = d*768 + (6*w8+t)*16 + u; orig gate row =
// (t>>1)*256 + 32*w8 + ((t&1)<<4) + u;  t in {0,1}=r, {2,3}=z, {4,5}=n.

// ---------------------------------------------------------------------------
// Phase 1: gate table (R9).  grid (2 dirs, 128 M-slices), 512 threads.
// ---------------------------------------------------------------------------
__global__ __launch_bounds__(512, 2)
void gru_table_kernel(const float* __restrict__ emb,
                      const float* __restrict__ Wih_f, const float* __restrict__ bih_f,
                      const float* __restrict__ bhh_f,
                      const float* __restrict__ Wih_b, const float* __restrict__ bih_b,
                      const float* __restrict__ bhh_b,
                      unsigned short* __restrict__ G) {
    __shared__ unsigned short aS[2][16 * HB_STR];    // dbuf emb tile (bf16)

    const int tid  = threadIdx.x;
    const int lane = tid & 63;
    const int w    = tid >> 6;       // wave 0..7 -> N-tiles 6w..6w+5
    const int u    = lane & 15;
    const int q    = lane >> 4;
    const int d    = blockIdx.x;     // 0 fwd, 1 bwd
    const int by   = blockIdx.y;     // 0..127

    const float* Wih = d ? Wih_b : Wih_f;
    const float* bih = d ? bih_b : bih_f;
    const float* bhh = d ? bhh_b : bhh_f;

    s16x8 breg[48];
    float beta[6];
#pragma unroll
    for (int t = 0; t < 6; ++t) {
        const int orig = (t >> 1) * 256 + 32 * w + ((t & 1) << 4) + u;
        const float scl = (t < 4) ? SRF : SNF;
        beta[t] = (bih[orig] + ((t < 4) ? bhh[orig] : 0.0f)) * scl;
#pragma unroll
        for (int kt = 0; kt < 8; ++kt) {
            const float* p = Wih + orig * 256 + kt * 32 + q * 8;
            breg[t * 8 + kt] =
                pack_bf8(*(const float4*)p, *(const float4*)(p + 4), scl);
        }
    }

    const int srow = tid >> 5;
    const int sc8  = (tid & 31) * 8;

    {
        const float* p = emb + (size_t)(by * 16 + srow) * 256 + sc8;
        float4 e0 = *(const float4*)p, e1 = *(const float4*)(p + 4);
        unsigned* dp = (unsigned*)&aS[0][srow * HB_STR + sc8];
        dp[0] = pk2(e0.x, e0.y); dp[1] = pk2(e0.z, e0.w);
        dp[2] = pk2(e1.x, e1.y); dp[3] = pk2(e1.z, e1.w);
    }
    __syncthreads();

    const size_t colbase = (size_t)(d * 48 + 6 * w) * 16 + u;

    for (int i = 0;; ++i) {
        const int mt = by + i * 128;
        if (mt >= 1875) break;
        const int mtn = mt + 128;
        const bool has_next = (mtn < 1875);
        const int buf = i & 1;

        float4 e0, e1;
        if (has_next) {
            const float* p = emb + (size_t)(mtn * 16 + srow) * 256 + sc8;
            e0 = *(const float4*)p;
            e1 = *(const float4*)(p + 4);
        }

        const int v0 = mt * 16;
#pragma unroll
        for (int l = 0; l < 2; ++l) {
            f32x4 a0 = {0.f, 0.f, 0.f, 0.f}, a1 = a0, a2 = a0;
#pragma unroll
            for (int kt = 0; kt < 8; ++kt) {
                s16x8 af = *(const s16x8*)&aS[buf][u * HB_STR + kt * 32 + q * 8];
                a0 = mfma16(af, breg[(0 + l) * 8 + kt], a0);
                a1 = mfma16(af, breg[(2 + l) * 8 + kt], a1);
                a2 = mfma16(af, breg[(4 + l) * 8 + kt], a2);
            }
#pragma unroll
            for (int g = 0; g < 3; ++g) {
                const f32x4 a = (g == 0) ? a0 : (g == 1) ? a1 : a2;
                const int t = 2 * g + l;
                unsigned short* gp = G + (size_t)(v0 + q * 4) * GCOLS + colbase + t * 16;
#pragma unroll
                for (int r = 0; r < 4; ++r)
                    gp[(size_t)r * GCOLS] = f2bf(a[r] + beta[t]);
            }
        }
        if (has_next) {
            unsigned* dp = (unsigned*)&aS[buf ^ 1][srow * HB_STR + sc8];
            dp[0] = pk2(e0.x, e0.y); dp[1] = pk2(e0.z, e0.w);
            dp[2] = pk2(e1.x, e1.y); dp[3] = pk2(e1.z, e1.w);
        }
        __syncthreads();
    }
}

// ---------------------------------------------------------------------------
// Phase 2: recurrence. grid = 16 (dir = bx>>3, batch group = bx&7), 512 thr.
// Gate-major MFMA ordering; xg read at step top from prev-staged LDS.
// ---------------------------------------------------------------------------
__global__ __launch_bounds__(512, 2)
void gru_rnn_kernel(const int* __restrict__ inp,
                    const float* __restrict__ Whh_f, const float* __restrict__ bhh_f,
                    const float* __restrict__ Whh_b, const float* __restrict__ bhh_b,
                    const float* __restrict__ W_lin, const float* __restrict__ b_lin,
                    const unsigned short* __restrict__ G,
                    float* __restrict__ out) {
    __shared__ int            toks[16][513];          // 32.8 KB
    __shared__ unsigned short hB[2 * HBUF];           // 17.9 KB dbuf h (bf16)
    __shared__ unsigned short xgS[2][16][GP_STR];     // 66.0 KB dbuf xg (bf16)
    __shared__ float          bhnS[256];              // 1 KB
    __shared__ float          hs[16 * HS_STR];        // 16.6 KB epilogue

    const int tid  = threadIdx.x;
    const int lane = tid & 63;
    const int w    = tid >> 6;          // wave 0..7 (owns i in [32w,32w+32))
    const int b    = lane & 15;         // batch within group
    const int q    = lane >> 4;
    const int d    = blockIdx.x >> 3;   // 0 fwd, 1 bwd
    const int b0   = (blockIdx.x & 7) * 16;

    const float* Whh = d ? Whh_b : Whh_f;
    const float* bhh = d ? bhh_b : bhh_f;

    // W_hh as 48 A-fragments (pre-scaled): tile t = 2*gate + half.  192 regs.
    s16x8 wreg[48];
#pragma unroll
    for (int t = 0; t < 6; ++t) {
        const int orig = (t >> 1) * 256 + 32 * w + ((t & 1) << 4) + b;
        const float scl = (t < 4) ? SRF : SNF;
#pragma unroll
        for (int kt = 0; kt < 8; ++kt) {
            const float* p = Whh + orig * 256 + kt * 32 + q * 8;
            wreg[t * 8 + kt] =
                pack_bf8(*(const float4*)p, *(const float4*)(p + 4), scl);
        }
    }

    for (int i = tid; i < 16 * 512; i += 512) {
        int bb = i >> 9, t = i & 511;
        toks[bb][t] = inp[(b0 + bb) * 512 + t];
    }
    for (int i = tid; i < 2 * HBUF; i += 512) hB[i] = 0;   // h0 = 0
    if (tid < 256) bhnS[tid] = SNF * bhh[512 + tid];
    __syncthreads();

    // prologue: stage step-0 xg into xgS[0] (wave w stages batches 2w, 2w+1)
    {
        int t0 = d ? 511 : 0;
#pragma unroll
        for (int j = 0; j < 2; ++j) {
            int bb = 2 * w + j;
            int tok = toks[bb][t0];
            const unsigned short* gb = G + (size_t)tok * GCOLS + (d ? 512 : 0) + lane * 8;
            gload_lds16(gb,       &xgS[0][bb][0]);
            gload_lds16(gb + 512, &xgS[0][bb][512]);
        }
    }
    __syncthreads();   // drains vmcnt -> xgS[0] valid

    const int xoff = d ? 256 : 0;       // dir-window shift inside stored row
    const int hbq  = b * HB_STR + q * 8;
    float hreg[8];
#pragma unroll
    for (int i = 0; i < 8; ++i) hreg[i] = 0.f;

#pragma unroll 2
    for (int ts = 0; ts < 512; ++ts) {
        const int rb = (ts & 1) * HBUF;
        const int pn = (ts + 1) & 1;
        // 1) issue NEXT step's xg gather (async, zero VGPR cost)
        {
            int s1 = (ts < 511) ? ts + 1 : 511;
            int t1 = d ? 511 - s1 : s1;
#pragma unroll
            for (int j = 0; j < 2; ++j) {
                int bb = 2 * w + j;
                int tok = toks[bb][t1];
                const unsigned short* gb = G + (size_t)tok * GCOLS + (d ? 512 : 0) + lane * 8;
                gload_lds16(gb,       &xgS[pn][bb][0]);
                gload_lds16(gb + 512, &xgS[pn][bb][512]);
            }
        }
        // 2) read this step's xg at step TOP (staged last step -> ready now;
        //    unpacks overlap the MFMA chains below)
        const unsigned short* xrow = &xgS[ts & 1][b][xoff + 96 * w + 4 * q];
        uint2 uxr0 = *(const uint2*)&xrow[0];
        uint2 uxz0 = *(const uint2*)&xrow[32];
        uint2 uxn0 = *(const uint2*)&xrow[64];
        uint2 uxr1 = *(const uint2*)&xrow[16];
        uint2 uxz1 = *(const uint2*)&xrow[48];
        uint2 uxn1 = *(const uint2*)&xrow[80];

        // 3) two column-halves, GATE-MAJOR: pass A (r+z) -> rg/zg sig2s
        //    overlap pass B (n) MFMA drain; only tg chain exposed.
#pragma unroll
        for (int l = 0; l < 2; ++l) {
            const uint2 uxr = l ? uxr1 : uxr0;
            const uint2 uxz = l ? uxz1 : uxz0;
            const uint2 uxn = l ? uxn1 : uxn0;
            float xr[4] = {bf_lo(uxr.x), bf_hi(uxr.x), bf_lo(uxr.y), bf_hi(uxr.y)};
            float xz[4] = {bf_lo(uxz.x), bf_hi(uxz.x), bf_lo(uxz.y), bf_hi(uxz.y)};
            float xn[4] = {bf_lo(uxn.x), bf_hi(uxn.x), bf_lo(uxn.y), bf_hi(uxn.y)};

            // pass A: r and z gates (16 MFMA, 2 independent chains)
            f32x4 ar = {0.f, 0.f, 0.f, 0.f};
            f32x4 az = {0.f, 0.f, 0.f, 0.f};
#pragma unroll
            for (int kt = 0; kt < 8; ++kt) {
                s16x8 hf = *(const s16x8*)&hB[rb + hbq + kt * 32];
                ar = mfma16(wreg[(0 + l) * 8 + kt], hf, ar);
                az = mfma16(wreg[(2 + l) * 8 + kt], hf, az);
            }
            // pass B: n gate (8 MFMA) — rg/zg trans scheduled into its shadow
            f32x4 an = *(const f32x4*)&bhnS[32 * w + 16 * l + 4 * q];
#pragma unroll
            for (int kt = 0; kt < 8; ++kt) {
                s16x8 hf = *(const s16x8*)&hB[rb + hbq + kt * 32];
                an = mfma16(wreg[(4 + l) * 8 + kt], hf, an);
            }
            float rg[4], zg[4];
#pragma unroll
            for (int r = 0; r < 4; ++r) {
                rg[r] = sig2(xr[r] + ar[r]);
                zg[r] = sig2(xz[r] + az[r]);
            }
#pragma unroll
            for (int r = 0; r < 4; ++r) {
                float tg = sig2(fmaf(rg[r], an[r], xn[r]));
                float ng = fmaf(-2.0f, tg, 1.0f);
                const int i = l * 4 + r;
                hreg[i] = fmaf(zg[r], hreg[i] - ng, ng);
            }
            // write this half's h_new (bf16) to the other h buffer
            unsigned p0 = pk2(hreg[l * 4 + 0], hreg[l * 4 + 1]);
            unsigned p1 = pk2(hreg[l * 4 + 2], hreg[l * 4 + 3]);
            *(uint2*)&hB[pn * HBUF + b * HB_STR + 32 * w + 16 * l + 4 * q] =
                make_uint2(p0, p1);
        }
        // 4) one barrier: drains lgkm (h writes) + vmcnt (xg stage) together
        __syncthreads();
    }

    // epilogue: out[b][c] += h_d[b] . W_lin[c, d*256:+256]  (+ b_lin once)
#pragma unroll
    for (int l = 0; l < 2; ++l) {
        f32x4 v = {hreg[l * 4 + 0], hreg[l * 4 + 1],
                   hreg[l * 4 + 2], hreg[l * 4 + 3]};
        *(f32x4*)&hs[b * HS_STR + 32 * w + 16 * l + 4 * q] = v;
    }
    __syncthreads();
    if (tid < 160) {
        int bb = tid / 10;
        int c  = tid - bb * 10;
        float acc = d ? 0.0f : b_lin[c];
        const float* wl = W_lin + c * 512 + d * 256;
        const float* hp = &hs[bb * HS_STR];
        for (int i = 0; i < 256; ++i) acc += hp[i] * wl[i];
        atomicAdd(&out[(b0 + bb) * 10 + c], acc);
    }
}

// ---------------------------------------------------------------------------
extern "C" void kernel_launch(void* const* d_in, const int* in_sizes, int n_in,
                              void* d_out, int out_size, void* d_ws, size_t ws_size,
                              hipStream_t stream) {
    const int*   inp   = (const int*)d_in[0];
    const float* emb   = (const float*)d_in[1];
    const float* Wih_f = (const float*)d_in[2];
    const float* Whh_f = (const float*)d_in[3];
    const float* bih_f = (const float*)d_in[4];
    const float* bhh_f = (const float*)d_in[5];
    const float* Wih_b = (const float*)d_in[6];
    const float* Whh_b = (const float*)d_in[7];
    const float* bih_b = (const float*)d_in[8];
    const float* bhh_b = (const float*)d_in[9];
    const float* W_lin = (const float*)d_in[10];
    const float* b_lin = (const float*)d_in[11];
    float* out = (float*)d_out;
    unsigned short* G = (unsigned short*)d_ws;   // 30000*1536*2 B = 92.16 MB

    hipMemsetAsync(d_out, 0, (size_t)out_size * sizeof(float), stream);
    hipLaunchKernelGGL(gru_table_kernel, dim3(2, 128), dim3(512), 0, stream,
                       emb, Wih_f, bih_f, bhh_f, Wih_b, bih_b, bhh_b, G);
    hipLaunchKernelGGL(gru_rnn_kernel, dim3(16), dim3(512), 0, stream,
                       inp, Whh_f, bhh_f, Whh_b, bhh_b, W_lin, b_lin, G, out);
}